// Round 1
// baseline (894.636 us; speedup 1.0000x reference)
//
#include <hip/hip_runtime.h>
#include <math.h>

#define NTOT 32768   // B*NP
#define NPG  4096    // nodes per graph
#define BGR  8       // graphs
#define KK   1024    // top-k
#define NN   8192    // B*K kept nodes
#define NE   262144  // edges

// ---------------- init ----------------
__global__ void k_init(int* remap, int* deg, int* cnt) {
    int i = blockIdx.x * blockDim.x + threadIdx.x;
    if (i < NTOT) remap[i] = -1;
    if (i < NN) deg[i] = 0;
    if (i == 0) *cnt = 0;
}

// ---------------- top-k per graph (bitonic sort in LDS) ----------------
__global__ __launch_bounds__(1024) void k_topk(const float* __restrict__ pos,
                                               const float* __restrict__ p,
                                               int* __restrict__ remap,
                                               float* __restrict__ x0) {
    __shared__ float sv[NPG];
    __shared__ int   si[NPG];
    const int g = blockIdx.x;
    const int tid = threadIdx.x;
    const float p0 = p[0], p1 = p[1], p2 = p[2];
    const float invn = 1.0f / sqrtf(p0 * p0 + p1 * p1 + p2 * p2);

    for (int i = tid; i < NPG; i += 1024) {
        const float* pp = pos + (size_t)(g * NPG + i) * 3;
        float d = pp[0] * p0 + pp[1] * p1 + pp[2] * p2;
        sv[i] = tanhf(d * invn);
        si[i] = i;
    }
    __syncthreads();

    // bitonic sort, "ascending" by before(a,b) = (a.v > b.v) || (v equal && a.i < b.i)
    // => final order is descending by value, ties by lower index first.
    for (int k = 2; k <= NPG; k <<= 1) {
        for (int j = k >> 1; j > 0; j >>= 1) {
            for (int i = tid; i < NPG; i += 1024) {
                int l = i ^ j;
                if (l > i) {
                    bool dir = ((i & k) == 0);
                    float vi = sv[i], vl = sv[l];
                    int   ii = si[i], il = si[l];
                    bool lt = (vl > vi) || (vl == vi && il < ii);  // before(l, i)
                    if (lt == dir) {
                        sv[i] = vl; sv[l] = vi;
                        si[i] = il; si[l] = ii;
                    }
                }
            }
            __syncthreads();
        }
    }

    for (int j = tid; j < KK; j += 1024) {
        int idx = si[j];
        float val = sv[j];
        int go = g * NPG + idx;
        int nn = g * KK + j;
        remap[go] = nn;
        x0[(size_t)nn * 3 + 0] = pos[(size_t)go * 3 + 0] * val;
        x0[(size_t)nn * 3 + 1] = pos[(size_t)go * 3 + 1] * val;
        x0[(size_t)nn * 3 + 2] = pos[(size_t)go * 3 + 2] * val;
    }
}

// ---------------- edge compaction + in-degree ----------------
__global__ void k_edges(const int* __restrict__ ei, const int* __restrict__ remap,
                        int* esrc, int* edst, int* deg, int* cnt) {
    int e = blockIdx.x * blockDim.x + threadIdx.x;
    if (e >= NE) return;
    int s = remap[ei[e]];
    int d = remap[ei[NE + e]];
    if (s >= 0 && d >= 0) {
        int pos = atomicAdd(cnt, 1);
        esrc[pos] = s;
        edst[pos] = d;
        atomicAdd(&deg[d], 1);
    }
}

__global__ void k_dinv(const int* __restrict__ deg, float* dinv, float* dinv2) {
    int n = blockIdx.x * blockDim.x + threadIdx.x;
    if (n < NN) {
        float dd = (float)(deg[n] + 1);
        float r = 1.0f / sqrtf(dd);
        dinv[n] = r;
        dinv2[n] = r * r;
    }
}

__global__ void k_enorm(const int* __restrict__ esrc, const int* __restrict__ edst,
                        const float* __restrict__ dinv, float* enorm, const int* cnt) {
    int n = *cnt;
    for (int e = blockIdx.x * blockDim.x + threadIdx.x; e < n; e += gridDim.x * blockDim.x)
        enorm[e] = dinv[esrc[e]] * dinv[edst[e]];
}

// ---------------- tiled f32 matmul: C[8192,Nc] = A[8192,Kd] @ W[Kd,Nc] ----------------
#define BM 64
#define BN 64
#define BKT 16
__global__ __launch_bounds__(256) void k_mm(const float* __restrict__ A,
                                            const float* __restrict__ W,
                                            float* __restrict__ C, int Kd, int Nc) {
    __shared__ float As[BM][BKT + 1];
    __shared__ float Bs[BKT][BN + 1];
    const int bm = blockIdx.x * BM;
    const int bn = blockIdx.y * BN;
    const int tid = threadIdx.x;
    const int tx = tid & 15, ty = tid >> 4;
    float acc[4][4] = {};

    for (int k0 = 0; k0 < Kd; k0 += BKT) {
        for (int t = 0; t < 4; ++t) {
            int i = tid + t * 256;
            int m = i >> 4, k = i & 15;
            As[m][k] = (k0 + k < Kd) ? A[(size_t)(bm + m) * Kd + k0 + k] : 0.0f;
        }
        for (int t = 0; t < 4; ++t) {
            int i = tid + t * 256;
            int k = i >> 6, n = i & 63;
            Bs[k][n] = (k0 + k < Kd) ? W[(size_t)(k0 + k) * Nc + bn + n] : 0.0f;
        }
        __syncthreads();
        for (int k = 0; k < BKT; ++k) {
            float a[4], b[4];
#pragma unroll
            for (int i = 0; i < 4; ++i) a[i] = As[ty * 4 + i][k];
#pragma unroll
            for (int j = 0; j < 4; ++j) b[j] = Bs[k][tx * 4 + j];
#pragma unroll
            for (int i = 0; i < 4; ++i)
#pragma unroll
                for (int j = 0; j < 4; ++j) acc[i][j] += a[i] * b[j];
        }
        __syncthreads();
    }
    for (int i = 0; i < 4; ++i)
        for (int j = 0; j < 4; ++j)
            C[(size_t)(bm + ty * 4 + i) * Nc + bn + tx * 4 + j] = acc[i][j];
}

// ---------------- out = h*dinv2[n] + bias[c] ----------------
__global__ void k_selfbias(const float* __restrict__ h, const float* __restrict__ dinv2,
                           const float* __restrict__ bb, float* __restrict__ out, int Nc) {
    int i = blockIdx.x * blockDim.x + threadIdx.x;
    if (i < NN * Nc) {
        int n = i / Nc;
        int c = i - n * Nc;
        out[i] = h[i] * dinv2[n] + bb[c];
    }
}

// ---------------- scatter: out[dst] += h[src] * enorm (grid-stride, dynamic cnt) ----------------
__global__ void k_scatter(const float* __restrict__ h, const int* __restrict__ esrc,
                          const int* __restrict__ edst, const float* __restrict__ enorm,
                          float* out, const int* cnt, int Nc, int logNc) {
    long long total = ((long long)(*cnt)) << logNc;
    long long stride = (long long)gridDim.x * blockDim.x;
    for (long long t = (long long)blockIdx.x * blockDim.x + threadIdx.x; t < total; t += stride) {
        int e = (int)(t >> logNc);
        int c = (int)(t & (Nc - 1));
        atomicAdd(&out[(size_t)edst[e] * Nc + c], h[(size_t)esrc[e] * Nc + c] * enorm[e]);
    }
}

// ---------------- BN stats stage 1: 32 blocks x 256 rows, deterministic ----------------
__global__ __launch_bounds__(256) void k_bn1(const float* __restrict__ x,
                                             float* psum, float* psq, int Nc) {
    const int blk = blockIdx.x;
    const int tid = threadIdx.x;
    float s0 = 0, q0 = 0, s1 = 0, q1 = 0;
    for (int r = 0; r < 256; ++r) {
        const float* xr = x + (size_t)(blk * 256 + r) * Nc;
        if (tid < Nc) { float v = xr[tid]; s0 += v; q0 += v * v; }
        if (Nc > 256) { float v = xr[256 + tid]; s1 += v; q1 += v * v; }
    }
    if (tid < Nc) { psum[blk * Nc + tid] = s0; psq[blk * Nc + tid] = q0; }
    if (Nc > 256) { psum[blk * Nc + 256 + tid] = s1; psq[blk * Nc + 256 + tid] = q1; }
}

// ---------------- BN stats stage 2 ----------------
__global__ void k_bn2(const float* __restrict__ psum, const float* __restrict__ psq,
                      const float* __restrict__ g, const float* __restrict__ be,
                      float* scale, float* shift, int Nc) {
    int c = blockIdx.x * blockDim.x + threadIdx.x;
    if (c >= Nc) return;
    double s = 0, q = 0;
    for (int b = 0; b < 32; ++b) { s += psum[b * Nc + c]; q += psq[b * Nc + c]; }
    double mean = s / 8192.0;
    double var = q / 8192.0 - mean * mean;
    float sc = (float)((double)g[c] / sqrt(var + 1e-5));
    scale[c] = sc;
    shift[c] = be[c] - (float)mean * sc;
}

__global__ void k_bnapply(float* x, const float* __restrict__ scale,
                          const float* __restrict__ shift, int Nc) {
    int i = blockIdx.x * blockDim.x + threadIdx.x;
    if (i < NN * Nc) {
        int c = i & (Nc - 1);
        float v = x[i] * scale[c] + shift[c];
        x[i] = v > 0.0f ? v : 0.0f;
    }
}

// ---------------- global sum pool: [8,512] ----------------
__global__ void k_pool(const float* __restrict__ x, float* pooled) {
    int g = blockIdx.x >> 1;
    int c = ((blockIdx.x & 1) << 8) + threadIdx.x;
    float s = 0;
    for (int r = 0; r < KK; ++r) s += x[(size_t)(g * KK + r) * 512 + c];
    pooled[g * 512 + c] = s;
}

// ---------------- small FC + relu ----------------
__global__ void k_fc(const float* __restrict__ in, const float* __restrict__ W,
                     const float* __restrict__ bias, float* out, int fi, int fo) {
    __shared__ float row[512];
    int g = blockIdx.x, tid = threadIdx.x;
    for (int k = tid; k < fi; k += blockDim.x) row[k] = in[g * fi + k];
    __syncthreads();
    if (tid < fo) {
        float acc = bias[tid];
        for (int k = 0; k < fi; ++k) acc += row[k] * W[k * fo + tid];
        out[g * fo + tid] = acc > 0.0f ? acc : 0.0f;
    }
}

// ---------------- FC3 + log_softmax ----------------
__global__ void k_fc3(const float* __restrict__ in, const float* __restrict__ W,
                      const float* __restrict__ bias, float* out) {
    __shared__ float row[256];
    __shared__ float logits[100];
    __shared__ float red[128];
    int g = blockIdx.x, tid = threadIdx.x;  // 128 threads
    for (int k = tid; k < 256; k += 128) row[k] = in[g * 256 + k];
    __syncthreads();
    float v = -INFINITY;
    if (tid < 100) {
        float acc = bias[tid];
        for (int k = 0; k < 256; ++k) acc += row[k] * W[k * 100 + tid];
        logits[tid] = acc;
        v = acc;
    }
    red[tid] = v;
    __syncthreads();
    for (int s = 64; s > 0; s >>= 1) {
        if (tid < s) red[tid] = fmaxf(red[tid], red[tid + s]);
        __syncthreads();
    }
    float mx = red[0];
    __syncthreads();
    red[tid] = (tid < 100) ? expf(logits[tid] - mx) : 0.0f;
    __syncthreads();
    for (int s = 64; s > 0; s >>= 1) {
        if (tid < s) red[tid] += red[tid + s];
        __syncthreads();
    }
    float lse = logf(red[0]);
    if (tid < 100) out[g * 100 + tid] = logits[tid] - mx - lse;
}

// ---------------- launch ----------------
extern "C" void kernel_launch(void* const* d_in, const int* in_sizes, int n_in,
                              void* d_out, int out_size, void* d_ws, size_t ws_size,
                              hipStream_t stream) {
    const float* pos = (const float*)d_in[0];
    const int* ei = (const int*)d_in[1];
    const float* p = (const float*)d_in[3];
    const float *W[5], *bb[5], *gg[5], *be[5];
    for (int i = 0; i < 5; ++i) {
        W[i]  = (const float*)d_in[4 + 4 * i];
        bb[i] = (const float*)d_in[5 + 4 * i];
        gg[i] = (const float*)d_in[6 + 4 * i];
        be[i] = (const float*)d_in[7 + 4 * i];
    }
    const float* fw1 = (const float*)d_in[24]; const float* fb1 = (const float*)d_in[25];
    const float* fw2 = (const float*)d_in[26]; const float* fb2 = (const float*)d_in[27];
    const float* fw3 = (const float*)d_in[28]; const float* fb3 = (const float*)d_in[29];
    float* out = (float*)d_out;

    char* w = (char*)d_ws;
    float* A     = (float*)w; w += (size_t)NN * 512 * 4;
    float* Bq    = (float*)w; w += (size_t)NN * 512 * 4;
    int*   remap = (int*)w;   w += (size_t)NTOT * 4;
    int*   deg   = (int*)w;   w += NN * 4;
    float* dinv  = (float*)w; w += NN * 4;
    float* dinv2 = (float*)w; w += NN * 4;
    int*   esrc  = (int*)w;   w += (size_t)NE * 4;
    int*   edst  = (int*)w;   w += (size_t)NE * 4;
    float* enorm = (float*)w; w += (size_t)NE * 4;
    int*   cnt   = (int*)w;   w += 256;
    float* psum  = (float*)w; w += 32 * 512 * 4;
    float* psq   = (float*)w; w += 32 * 512 * 4;
    float* scale = (float*)w; w += 512 * 4;
    float* shift = (float*)w; w += 512 * 4;
    float* pooled= (float*)w; w += 8 * 512 * 4;
    float* t1    = (float*)w; w += 8 * 256 * 4;
    float* t2    = (float*)w; w += 8 * 256 * 4;

    k_init<<<NTOT / 256, 256, 0, stream>>>(remap, deg, cnt);
    k_topk<<<BGR, 1024, 0, stream>>>(pos, p, remap, A);
    k_edges<<<NE / 256, 256, 0, stream>>>(ei, remap, esrc, edst, deg, cnt);
    k_dinv<<<NN / 256, 256, 0, stream>>>(deg, dinv, dinv2);
    k_enorm<<<128, 256, 0, stream>>>(esrc, edst, dinv, enorm, cnt);

    const int fins[5]  = {3, 64, 128, 128, 256};
    const int fouts[5] = {64, 128, 128, 256, 512};
    for (int l = 0; l < 5; ++l) {
        int fi = fins[l], fo = fouts[l];
        dim3 mg(NN / BM, fo / BN);
        k_mm<<<mg, 256, 0, stream>>>(A, W[l], Bq, fi, fo);
        int tot = NN * fo;
        k_selfbias<<<(tot + 255) / 256, 256, 0, stream>>>(Bq, dinv2, bb[l], A, fo);
        int logf_ = (fo == 64) ? 6 : (fo == 128) ? 7 : (fo == 256) ? 8 : 9;
        k_scatter<<<1024, 256, 0, stream>>>(Bq, esrc, edst, enorm, A, cnt, fo, logf_);
        k_bn1<<<32, 256, 0, stream>>>(A, psum, psq, fo);
        k_bn2<<<2, 256, 0, stream>>>(psum, psq, gg[l], be[l], scale, shift, fo);
        k_bnapply<<<(tot + 255) / 256, 256, 0, stream>>>(A, scale, shift, fo);
    }

    k_pool<<<16, 256, 0, stream>>>(A, pooled);
    k_fc<<<8, 256, 0, stream>>>(pooled, fw1, fb1, t1, 512, 256);
    k_fc<<<8, 256, 0, stream>>>(t1, fw2, fb2, t2, 256, 256);
    k_fc3<<<8, 128, 0, stream>>>(t2, fw3, fb3, out);
}

// Round 2
// 737.181 us; speedup vs baseline: 1.2136x; 1.2136x over previous
//
#include <hip/hip_runtime.h>
#include <math.h>

#define NTOT 32768   // B*NP
#define NPG  4096    // nodes per graph
#define BGR  8       // graphs
#define KK   1024    // top-k
#define NN   8192    // B*K kept nodes
#define NE   262144  // edges

// ---------------- init ----------------
__global__ void k_init(int* remap, int* deg, int* cnt) {
    int i = blockIdx.x * blockDim.x + threadIdx.x;
    if (i < NTOT) remap[i] = -1;
    if (i < NN) deg[i] = 0;
    if (i == 0) *cnt = 0;
}

// ---------------- top-k per graph (bitonic sort in LDS) ----------------
__global__ __launch_bounds__(1024) void k_topk(const float* __restrict__ pos,
                                               const float* __restrict__ p,
                                               int* __restrict__ remap,
                                               float* __restrict__ x0) {
    __shared__ float sv[NPG];
    __shared__ int   si[NPG];
    const int g = blockIdx.x;
    const int tid = threadIdx.x;
    const float p0 = p[0], p1 = p[1], p2 = p[2];
    const float invn = 1.0f / sqrtf(p0 * p0 + p1 * p1 + p2 * p2);

    for (int i = tid; i < NPG; i += 1024) {
        const float* pp = pos + (size_t)(g * NPG + i) * 3;
        float d = pp[0] * p0 + pp[1] * p1 + pp[2] * p2;
        sv[i] = tanhf(d * invn);
        si[i] = i;
    }
    __syncthreads();

    // bitonic sort: final order descending by value, ties by lower index first.
    for (int k = 2; k <= NPG; k <<= 1) {
        for (int j = k >> 1; j > 0; j >>= 1) {
            for (int i = tid; i < NPG; i += 1024) {
                int l = i ^ j;
                if (l > i) {
                    bool dir = ((i & k) == 0);
                    float vi = sv[i], vl = sv[l];
                    int   ii = si[i], il = si[l];
                    bool lt = (vl > vi) || (vl == vi && il < ii);  // before(l, i)
                    if (lt == dir) {
                        sv[i] = vl; sv[l] = vi;
                        si[i] = il; si[l] = ii;
                    }
                }
            }
            __syncthreads();
        }
    }

    for (int j = tid; j < KK; j += 1024) {
        int idx = si[j];
        float val = sv[j];
        int go = g * NPG + idx;
        int nn = g * KK + j;
        remap[go] = nn;
        x0[(size_t)nn * 3 + 0] = pos[(size_t)go * 3 + 0] * val;
        x0[(size_t)nn * 3 + 1] = pos[(size_t)go * 3 + 1] * val;
        x0[(size_t)nn * 3 + 2] = pos[(size_t)go * 3 + 2] * val;
    }
}

// ---------------- edge compaction + in-degree ----------------
__global__ void k_edges(const int* __restrict__ ei, const int* __restrict__ remap,
                        int* esrc, int* edst, int* deg, int* cnt) {
    int e = blockIdx.x * blockDim.x + threadIdx.x;
    if (e >= NE) return;
    int s = remap[ei[e]];
    int d = remap[ei[NE + e]];
    if (s >= 0 && d >= 0) {
        int pos = atomicAdd(cnt, 1);
        esrc[pos] = s;
        edst[pos] = d;
        atomicAdd(&deg[d], 1);
    }
}

__global__ void k_dinv(const int* __restrict__ deg, float* dinv, float* dinv2) {
    int n = blockIdx.x * blockDim.x + threadIdx.x;
    if (n < NN) {
        float dd = (float)(deg[n] + 1);
        float r = 1.0f / sqrtf(dd);
        dinv[n] = r;
        dinv2[n] = r * r;
    }
}

__global__ void k_enorm(const int* __restrict__ esrc, const int* __restrict__ edst,
                        const float* __restrict__ dinv, float* enorm, const int* cnt) {
    int n = *cnt;
    for (int e = blockIdx.x * blockDim.x + threadIdx.x; e < n; e += gridDim.x * blockDim.x)
        enorm[e] = dinv[esrc[e]] * dinv[edst[e]];
}

// ---------------- tiled f32 matmul: C[8192,Nc] = A[8192,Kd] @ W[Kd,Nc] ----------------
#define BM 64
#define BN 64
#define BKT 16
__global__ __launch_bounds__(256) void k_mm(const float* __restrict__ A,
                                            const float* __restrict__ W,
                                            float* __restrict__ C, int Kd, int Nc) {
    __shared__ float As[BM][BKT + 1];
    __shared__ float Bs[BKT][BN + 1];
    const int bm = blockIdx.x * BM;
    const int bn = blockIdx.y * BN;
    const int tid = threadIdx.x;
    const int tx = tid & 15, ty = tid >> 4;
    float acc[4][4] = {};

    for (int k0 = 0; k0 < Kd; k0 += BKT) {
        for (int t = 0; t < 4; ++t) {
            int i = tid + t * 256;
            int m = i >> 4, k = i & 15;
            As[m][k] = (k0 + k < Kd) ? A[(size_t)(bm + m) * Kd + k0 + k] : 0.0f;
        }
        for (int t = 0; t < 4; ++t) {
            int i = tid + t * 256;
            int k = i >> 6, n = i & 63;
            Bs[k][n] = (k0 + k < Kd) ? W[(size_t)(k0 + k) * Nc + bn + n] : 0.0f;
        }
        __syncthreads();
        for (int k = 0; k < BKT; ++k) {
            float a[4], b[4];
#pragma unroll
            for (int i = 0; i < 4; ++i) a[i] = As[ty * 4 + i][k];
#pragma unroll
            for (int j = 0; j < 4; ++j) b[j] = Bs[k][tx * 4 + j];
#pragma unroll
            for (int i = 0; i < 4; ++i)
#pragma unroll
                for (int j = 0; j < 4; ++j) acc[i][j] += a[i] * b[j];
        }
        __syncthreads();
    }
    for (int i = 0; i < 4; ++i)
        for (int j = 0; j < 4; ++j)
            C[(size_t)(bm + ty * 4 + i) * Nc + bn + tx * 4 + j] = acc[i][j];
}

// ---------------- out = h*dinv2[n] + bias[c] ----------------
__global__ void k_selfbias(const float* __restrict__ h, const float* __restrict__ dinv2,
                           const float* __restrict__ bb, float* __restrict__ out, int Nc) {
    int i = blockIdx.x * blockDim.x + threadIdx.x;
    if (i < NN * Nc) {
        int n = i / Nc;
        int c = i - n * Nc;
        out[i] = h[i] * dinv2[n] + bb[c];
    }
}

// ---------------- scatter: out[dst] += h[src] * enorm (grid-stride, dynamic cnt) ----------------
__global__ void k_scatter(const float* __restrict__ h, const int* __restrict__ esrc,
                          const int* __restrict__ edst, const float* __restrict__ enorm,
                          float* out, const int* cnt, int Nc, int logNc) {
    long long total = ((long long)(*cnt)) << logNc;
    long long stride = (long long)gridDim.x * blockDim.x;
    for (long long t = (long long)blockIdx.x * blockDim.x + threadIdx.x; t < total; t += stride) {
        int e = (int)(t >> logNc);
        int c = (int)(t & (Nc - 1));
        atomicAdd(&out[(size_t)edst[e] * Nc + c], h[(size_t)esrc[e] * Nc + c] * enorm[e]);
    }
}

// ---------------- BN stats stage 1: 512 row-chunks x 16 rows, deterministic ----------------
#define BN1_ROWS 16
#define BN1_CHUNKS (NN / BN1_ROWS)   // 512
__global__ __launch_bounds__(256) void k_bn1(const float* __restrict__ x,
                                             float* __restrict__ psum,
                                             float* __restrict__ psq, int Nc) {
    const int chunk = blockIdx.x;
    const int r0 = chunk * BN1_ROWS;
    const int tid = threadIdx.x;
    for (int c = tid; c < Nc; c += 256) {
        float s = 0.0f, q = 0.0f;
#pragma unroll
        for (int r = 0; r < BN1_ROWS; ++r) {
            float v = x[(size_t)(r0 + r) * Nc + c];
            s += v; q += v * v;
        }
        psum[(size_t)chunk * Nc + c] = s;
        psq[(size_t)chunk * Nc + c]  = q;
    }
}

// ---------------- BN stats stage 2 ----------------
__global__ void k_bn2(const float* __restrict__ psum, const float* __restrict__ psq,
                      const float* __restrict__ g, const float* __restrict__ be,
                      float* scale, float* shift, int Nc) {
    int c = blockIdx.x * blockDim.x + threadIdx.x;
    if (c >= Nc) return;
    double s = 0, q = 0;
    for (int b = 0; b < BN1_CHUNKS; ++b) { s += psum[(size_t)b * Nc + c]; q += psq[(size_t)b * Nc + c]; }
    double mean = s / 8192.0;
    double var = q / 8192.0 - mean * mean;
    float sc = (float)((double)g[c] / sqrt(var + 1e-5));
    scale[c] = sc;
    shift[c] = be[c] - (float)mean * sc;
}

__global__ void k_bnapply(float* x, const float* __restrict__ scale,
                          const float* __restrict__ shift, int Nc) {
    int i = blockIdx.x * blockDim.x + threadIdx.x;
    if (i < NN * Nc) {
        int c = i & (Nc - 1);
        float v = x[i] * scale[c] + shift[c];
        x[i] = v > 0.0f ? v : 0.0f;
    }
}

// ---------------- global sum pool: [8,512], 64 blocks ----------------
__global__ __launch_bounds__(256) void k_pool(const float* __restrict__ x, float* pooled) {
    __shared__ float red[4][64];
    int g = blockIdx.x >> 3;
    int c0 = (blockIdx.x & 7) * 64;
    int c = threadIdx.x & 63;
    int rp = threadIdx.x >> 6;   // 0..3
    float s = 0;
    for (int r = rp; r < KK; r += 4)
        s += x[(size_t)(g * KK + r) * 512 + c0 + c];
    red[rp][c] = s;
    __syncthreads();
    if (rp == 0)
        pooled[g * 512 + c0 + c] = red[0][c] + red[1][c] + red[2][c] + red[3][c];
}

// ---------------- small FC + relu ----------------
__global__ void k_fc(const float* __restrict__ in, const float* __restrict__ W,
                     const float* __restrict__ bias, float* out, int fi, int fo) {
    __shared__ float row[512];
    int g = blockIdx.x, tid = threadIdx.x;
    for (int k = tid; k < fi; k += blockDim.x) row[k] = in[g * fi + k];
    __syncthreads();
    if (tid < fo) {
        float acc = bias[tid];
        for (int k = 0; k < fi; ++k) acc += row[k] * W[k * fo + tid];
        out[g * fo + tid] = acc > 0.0f ? acc : 0.0f;
    }
}

// ---------------- FC3 + log_softmax ----------------
__global__ void k_fc3(const float* __restrict__ in, const float* __restrict__ W,
                      const float* __restrict__ bias, float* out) {
    __shared__ float row[256];
    __shared__ float logits[100];
    __shared__ float red[128];
    int g = blockIdx.x, tid = threadIdx.x;  // 128 threads
    for (int k = tid; k < 256; k += 128) row[k] = in[g * 256 + k];
    __syncthreads();
    float v = -INFINITY;
    if (tid < 100) {
        float acc = bias[tid];
        for (int k = 0; k < 256; ++k) acc += row[k] * W[k * 100 + tid];
        logits[tid] = acc;
        v = acc;
    }
    red[tid] = v;
    __syncthreads();
    for (int s = 64; s > 0; s >>= 1) {
        if (tid < s) red[tid] = fmaxf(red[tid], red[tid + s]);
        __syncthreads();
    }
    float mx = red[0];
    __syncthreads();
    red[tid] = (tid < 100) ? expf(logits[tid] - mx) : 0.0f;
    __syncthreads();
    for (int s = 64; s > 0; s >>= 1) {
        if (tid < s) red[tid] += red[tid + s];
        __syncthreads();
    }
    float lse = logf(red[0]);
    if (tid < 100) out[g * 100 + tid] = logits[tid] - mx - lse;
}

// ---------------- launch ----------------
extern "C" void kernel_launch(void* const* d_in, const int* in_sizes, int n_in,
                              void* d_out, int out_size, void* d_ws, size_t ws_size,
                              hipStream_t stream) {
    const float* pos = (const float*)d_in[0];
    const int* ei = (const int*)d_in[1];
    const float* p = (const float*)d_in[3];
    const float *W[5], *bb[5], *gg[5], *be[5];
    for (int i = 0; i < 5; ++i) {
        W[i]  = (const float*)d_in[4 + 4 * i];
        bb[i] = (const float*)d_in[5 + 4 * i];
        gg[i] = (const float*)d_in[6 + 4 * i];
        be[i] = (const float*)d_in[7 + 4 * i];
    }
    const float* fw1 = (const float*)d_in[24]; const float* fb1 = (const float*)d_in[25];
    const float* fw2 = (const float*)d_in[26]; const float* fb2 = (const float*)d_in[27];
    const float* fw3 = (const float*)d_in[28]; const float* fb3 = (const float*)d_in[29];
    float* out = (float*)d_out;

    char* w = (char*)d_ws;
    float* A     = (float*)w; w += (size_t)NN * 512 * 4;
    float* Bq    = (float*)w; w += (size_t)NN * 512 * 4;
    int*   remap = (int*)w;   w += (size_t)NTOT * 4;
    int*   deg   = (int*)w;   w += NN * 4;
    float* dinv  = (float*)w; w += NN * 4;
    float* dinv2 = (float*)w; w += NN * 4;
    int*   esrc  = (int*)w;   w += (size_t)NE * 4;
    int*   edst  = (int*)w;   w += (size_t)NE * 4;
    float* enorm = (float*)w; w += (size_t)NE * 4;
    int*   cnt   = (int*)w;   w += 256;
    float* psum  = (float*)w; w += (size_t)BN1_CHUNKS * 512 * 4;
    float* psq   = (float*)w; w += (size_t)BN1_CHUNKS * 512 * 4;
    float* scale = (float*)w; w += 512 * 4;
    float* shift = (float*)w; w += 512 * 4;
    float* pooled= (float*)w; w += 8 * 512 * 4;
    float* t1    = (float*)w; w += 8 * 256 * 4;
    float* t2    = (float*)w; w += 8 * 256 * 4;

    k_init<<<NTOT / 256, 256, 0, stream>>>(remap, deg, cnt);
    k_topk<<<BGR, 1024, 0, stream>>>(pos, p, remap, A);
    k_edges<<<NE / 256, 256, 0, stream>>>(ei, remap, esrc, edst, deg, cnt);
    k_dinv<<<NN / 256, 256, 0, stream>>>(deg, dinv, dinv2);
    k_enorm<<<128, 256, 0, stream>>>(esrc, edst, dinv, enorm, cnt);

    const int fins[5]  = {3, 64, 128, 128, 256};
    const int fouts[5] = {64, 128, 128, 256, 512};
    for (int l = 0; l < 5; ++l) {
        int fi = fins[l], fo = fouts[l];
        dim3 mg(NN / BM, fo / BN);
        k_mm<<<mg, 256, 0, stream>>>(A, W[l], Bq, fi, fo);
        int tot = NN * fo;
        k_selfbias<<<(tot + 255) / 256, 256, 0, stream>>>(Bq, dinv2, bb[l], A, fo);
        int logf_ = (fo == 64) ? 6 : (fo == 128) ? 7 : (fo == 256) ? 8 : 9;
        k_scatter<<<1024, 256, 0, stream>>>(Bq, esrc, edst, enorm, A, cnt, fo, logf_);
        k_bn1<<<BN1_CHUNKS, 256, 0, stream>>>(A, psum, psq, fo);
        k_bn2<<<2, 256, 0, stream>>>(psum, psq, gg[l], be[l], scale, shift, fo);
        k_bnapply<<<(tot + 255) / 256, 256, 0, stream>>>(A, scale, shift, fo);
    }

    k_pool<<<64, 256, 0, stream>>>(A, pooled);
    k_fc<<<8, 256, 0, stream>>>(pooled, fw1, fb1, t1, 512, 256);
    k_fc<<<8, 256, 0, stream>>>(t1, fw2, fb2, t2, 256, 256);
    k_fc3<<<8, 128, 0, stream>>>(t2, fw3, fb3, out);
}

// Round 3
// 537.222 us; speedup vs baseline: 1.6653x; 1.3722x over previous
//
#include <hip/hip_runtime.h>
#include <math.h>

#define NTOT 32768   // B*NP
#define NPG  4096    // nodes per graph
#define BGR  8       // graphs
#define KK   1024    // top-k
#define NN   8192    // B*K kept nodes
#define NE   262144  // edges

// ---------------- init ----------------
__global__ void k_init(int* remap, int* deg, int* cnt) {
    int i = blockIdx.x * blockDim.x + threadIdx.x;
    if (i < NTOT) remap[i] = -1;
    if (i < NN) deg[i] = 0;
    if (i == 0) *cnt = 0;
}

// ---------------- top-k per graph: radix select + ordered compaction ----------------
// Keeps the exact lax.top_k set (value desc, index asc ties); rank order within a
// graph is irrelevant downstream (BN over all rows, per-graph sum pool).
__global__ __launch_bounds__(1024) void k_topk2(const float* __restrict__ pos,
                                                const float* __restrict__ p,
                                                int* __restrict__ remap,
                                                float* __restrict__ x0) {
    __shared__ unsigned skey[NPG];
    __shared__ float sval[NPG];
    __shared__ int hist[256];
    __shared__ int Sarr[256];
    __shared__ int wsum[16];
    __shared__ int s_bin, s_above;

    const int g = blockIdx.x, tid = threadIdx.x;
    const int lane = tid & 63, wid = tid >> 6;
    const float p0 = p[0], p1 = p[1], p2 = p[2];
    const float invn = 1.0f / sqrtf(p0 * p0 + p1 * p1 + p2 * p2);

    for (int i = tid; i < NPG; i += 1024) {
        const float* pp = pos + (size_t)(g * NPG + i) * 3;
        float s = tanhf((pp[0] * p0 + pp[1] * p1 + pp[2] * p2) * invn);
        sval[i] = s;
        unsigned b = __float_as_uint(s);
        skey[i] = (b & 0x80000000u) ? ~b : (b | 0x80000000u);  // larger float -> larger key
    }
    __syncthreads();

    // 4 rounds of 8-bit MSB-first radix select for the KK-th largest key
    unsigned prefix = 0;
    int needed = KK;
    for (int r = 0; r < 4; ++r) {
        const int sh = 24 - 8 * r;
        if (tid < 256) hist[tid] = 0;
        __syncthreads();
        for (int i = tid; i < NPG; i += 1024) {
            unsigned k = skey[i];
            bool act = (r == 0) || ((k >> (sh + 8)) == prefix);
            if (act) atomicAdd(&hist[(k >> sh) & 255u], 1);
        }
        __syncthreads();
        // suffix sums S[b] = sum_{j>=b} hist[j] (wave 0, 4 bins/lane)
        if (wid == 0) {
            int h0 = hist[4 * lane + 0], h1 = hist[4 * lane + 1];
            int h2 = hist[4 * lane + 2], h3 = hist[4 * lane + 3];
            int l3 = h3, l2 = h2 + l3, l1 = h1 + l2, l0 = h0 + l1;
            int t = l0;
            for (int off = 1; off < 64; off <<= 1) {
                int n = __shfl_down(t, off, 64);
                if (lane + off < 64) t += n;
            }
            int hi = t - l0;  // sum over lanes > lane
            Sarr[4 * lane + 0] = l0 + hi;
            Sarr[4 * lane + 1] = l1 + hi;
            Sarr[4 * lane + 2] = l2 + hi;
            Sarr[4 * lane + 3] = l3 + hi;
        }
        __syncthreads();
        if (tid < 256) {
            int Sb = Sarr[tid];
            int Sb1 = (tid < 255) ? Sarr[tid + 1] : 0;
            if (Sb >= needed && Sb1 < needed) { s_bin = tid; s_above = Sb1; }
        }
        __syncthreads();
        needed -= s_above;
        prefix = (prefix << 8) | (unsigned)s_bin;
        __syncthreads();
    }
    const unsigned Tkey = prefix;
    const int needTies = needed;  // ties kept = lowest indices

    // index-ordered compaction: 4 chunks of 1024, two block scans per chunk
    int tiebase = 0, keepbase = 0;
    for (int c = 0; c < 4; ++c) {
        const int i = c * 1024 + tid;
        const unsigned k = skey[i];
        const int tie = (k == Tkey) ? 1 : 0;
        // --- scan 1: tie mask ---
        int v = tie;
        for (int off = 1; off < 64; off <<= 1) {
            int n = __shfl_up(v, off, 64);
            if (lane >= off) v += n;
        }
        if (lane == 63) wsum[wid] = v;
        __syncthreads();
        if (wid == 0) {
            int w = (lane < 16) ? wsum[lane] : 0;
            for (int off = 1; off < 16; off <<= 1) {
                int n = __shfl_up(w, off, 64);
                if (lane >= off) w += n;
            }
            if (lane < 16) wsum[lane] = w;
        }
        __syncthreads();
        const int trank = tiebase + v + (wid > 0 ? wsum[wid - 1] : 0) - tie;  // exclusive
        const int ttot = wsum[15];
        const int keep = (k > Tkey) || (tie && trank < needTies);
        __syncthreads();
        // --- scan 2: keep mask ---
        int u = keep;
        for (int off = 1; off < 64; off <<= 1) {
            int n = __shfl_up(u, off, 64);
            if (lane >= off) u += n;
        }
        if (lane == 63) wsum[wid] = u;
        __syncthreads();
        if (wid == 0) {
            int w = (lane < 16) ? wsum[lane] : 0;
            for (int off = 1; off < 16; off <<= 1) {
                int n = __shfl_up(w, off, 64);
                if (lane >= off) w += n;
            }
            if (lane < 16) wsum[lane] = w;
        }
        __syncthreads();
        const int kincl = u + (wid > 0 ? wsum[wid - 1] : 0);
        const int ktot = wsum[15];
        if (keep) {
            int nn = g * KK + keepbase + kincl - 1;
            remap[g * NPG + i] = nn;
            float val = sval[i];
            const float* pp = pos + (size_t)(g * NPG + i) * 3;
            x0[(size_t)nn * 3 + 0] = pp[0] * val;
            x0[(size_t)nn * 3 + 1] = pp[1] * val;
            x0[(size_t)nn * 3 + 2] = pp[2] * val;
        }
        tiebase += ttot;
        keepbase += ktot;
        __syncthreads();
    }
}

// ---------------- edge compaction + in-degree ----------------
__global__ void k_edges(const int* __restrict__ ei, const int* __restrict__ remap,
                        int* esrc, int* edst, int* deg, int* cnt) {
    int e = blockIdx.x * blockDim.x + threadIdx.x;
    if (e >= NE) return;
    int s = remap[ei[e]];
    int d = remap[ei[NE + e]];
    if (s >= 0 && d >= 0) {
        int pos = atomicAdd(cnt, 1);
        esrc[pos] = s;
        edst[pos] = d;
        atomicAdd(&deg[d], 1);
    }
}

__global__ void k_enorm(const int* __restrict__ esrc, const int* __restrict__ edst,
                        const int* __restrict__ deg, float* enorm, const int* cnt) {
    int n = *cnt;
    for (int e = blockIdx.x * blockDim.x + threadIdx.x; e < n; e += gridDim.x * blockDim.x)
        enorm[e] = rsqrtf((float)(deg[esrc[e]] + 1)) * rsqrtf((float)(deg[edst[e]] + 1));
}

// ---------------- tiled f32 matmul + fused self-loop/bias epilogue ----------------
// H = A @ W ; if Y != null: Y = H / (deg+1) + bias  (scatter then accumulates into Y)
#define BM 64
#define BNT 64
#define BKT 16
__global__ __launch_bounds__(256) void k_mm(const float* __restrict__ A,
                                            const float* __restrict__ W,
                                            const int* __restrict__ deg,
                                            const float* __restrict__ bias,
                                            float* __restrict__ H,
                                            float* __restrict__ Y,
                                            int Kd, int Nc) {
    __shared__ float As[BM][BKT + 1];
    __shared__ float Bs[BKT][BNT + 1];
    const int bm = blockIdx.x * BM;
    const int bn = blockIdx.y * BNT;
    const int tid = threadIdx.x;
    const int tx = tid & 15, ty = tid >> 4;
    float acc[4][4] = {};

    for (int k0 = 0; k0 < Kd; k0 += BKT) {
        for (int t = 0; t < 4; ++t) {
            int i = tid + t * 256;
            int m = i >> 4, k = i & 15;
            As[m][k] = (k0 + k < Kd) ? A[(size_t)(bm + m) * Kd + k0 + k] : 0.0f;
        }
        for (int t = 0; t < 4; ++t) {
            int i = tid + t * 256;
            int k = i >> 6, n = i & 63;
            Bs[k][n] = (k0 + k < Kd) ? W[(size_t)(k0 + k) * Nc + bn + n] : 0.0f;
        }
        __syncthreads();
        for (int k = 0; k < BKT; ++k) {
            float a[4], b[4];
#pragma unroll
            for (int i = 0; i < 4; ++i) a[i] = As[ty * 4 + i][k];
#pragma unroll
            for (int j = 0; j < 4; ++j) b[j] = Bs[k][tx * 4 + j];
#pragma unroll
            for (int i = 0; i < 4; ++i)
#pragma unroll
                for (int j = 0; j < 4; ++j) acc[i][j] += a[i] * b[j];
        }
        __syncthreads();
    }
#pragma unroll
    for (int i = 0; i < 4; ++i) {
        int row = bm + ty * 4 + i;
        float4 h = make_float4(acc[i][0], acc[i][1], acc[i][2], acc[i][3]);
        *(float4*)&H[(size_t)row * Nc + bn + tx * 4] = h;
        if (Y) {
            float inv = 1.0f / (float)(deg[row] + 1);
            const float4 b4 = *(const float4*)&bias[bn + tx * 4];
            float4 y = make_float4(h.x * inv + b4.x, h.y * inv + b4.y,
                                   h.z * inv + b4.z, h.w * inv + b4.w);
            *(float4*)&Y[(size_t)row * Nc + bn + tx * 4] = y;
        }
    }
}

// fallback (unfused): out = h/(deg+1) + bias
__global__ void k_selfbias(const float* __restrict__ h, const int* __restrict__ deg,
                           const float* __restrict__ bb, float* __restrict__ out, int Nc) {
    int i = blockIdx.x * blockDim.x + threadIdx.x;
    if (i < NN * Nc) {
        int n = i / Nc;
        int c = i - n * Nc;
        out[i] = h[i] / (float)(deg[n] + 1) + bb[c];
    }
}

// ---------------- scatter: Y[dst] += H[src] * enorm ----------------
__global__ void k_scatter(const float* __restrict__ h, const int* __restrict__ esrc,
                          const int* __restrict__ edst, const float* __restrict__ enorm,
                          float* out, const int* cnt, int Nc, int logNc) {
    long long total = ((long long)(*cnt)) << logNc;
    long long stride = (long long)gridDim.x * blockDim.x;
    for (long long t = (long long)blockIdx.x * blockDim.x + threadIdx.x; t < total; t += stride) {
        int e = (int)(t >> logNc);
        int c = (int)(t & (Nc - 1));
        atomicAdd(&out[(size_t)edst[e] * Nc + c], h[(size_t)esrc[e] * Nc + c] * enorm[e]);
    }
}

// ---------------- BN stats stage 1: 256 row-chunks x 32 rows, deterministic ----------------
#define BN1_ROWS 32
#define BN1_CHUNKS (NN / BN1_ROWS)   // 256
__global__ __launch_bounds__(256) void k_bn1(const float* __restrict__ x,
                                             float* __restrict__ psum,
                                             float* __restrict__ psq, int Nc) {
    const int chunk = blockIdx.x;
    const int r0 = chunk * BN1_ROWS;
    const int tid = threadIdx.x;
    for (int c = tid; c < Nc; c += 256) {
        float s = 0.0f, q = 0.0f;
#pragma unroll
        for (int r = 0; r < BN1_ROWS; ++r) {
            float v = x[(size_t)(r0 + r) * Nc + c];
            s += v; q += v * v;
        }
        psum[(size_t)chunk * Nc + c] = s;
        psq[(size_t)chunk * Nc + c]  = q;
    }
}

__global__ void k_bn2(const float* __restrict__ psum, const float* __restrict__ psq,
                      const float* __restrict__ g, const float* __restrict__ be,
                      float* scale, float* shift, int Nc) {
    int c = blockIdx.x * blockDim.x + threadIdx.x;
    if (c >= Nc) return;
    double s = 0, q = 0;
    for (int b = 0; b < BN1_CHUNKS; ++b) { s += psum[(size_t)b * Nc + c]; q += psq[(size_t)b * Nc + c]; }
    double mean = s / 8192.0;
    double var = q / 8192.0 - mean * mean;
    float sc = (float)((double)g[c] / sqrt(var + 1e-5));
    scale[c] = sc;
    shift[c] = be[c] - (float)mean * sc;
}

// x = relu(x*scale + shift), float4
__global__ void k_bnapply(float* x, const float* __restrict__ scale,
                          const float* __restrict__ shift, int Nc) {
    int i = blockIdx.x * blockDim.x + threadIdx.x;  // vec4 index
    int c4 = i & ((Nc >> 2) - 1);
    float4 v = ((const float4*)x)[i];
    float4 sc = ((const float4*)scale)[c4];
    float4 sh = ((const float4*)shift)[c4];
    v.x = fmaxf(v.x * sc.x + sh.x, 0.0f);
    v.y = fmaxf(v.y * sc.y + sh.y, 0.0f);
    v.z = fmaxf(v.z * sc.z + sh.z, 0.0f);
    v.w = fmaxf(v.w * sc.w + sh.w, 0.0f);
    ((float4*)x)[i] = v;
}

// ---------------- global sum pool: [8,512], 64 blocks ----------------
__global__ __launch_bounds__(256) void k_pool(const float* __restrict__ x, float* pooled) {
    __shared__ float red[4][64];
    int g = blockIdx.x >> 3;
    int c0 = (blockIdx.x & 7) * 64;
    int c = threadIdx.x & 63;
    int rp = threadIdx.x >> 6;
    float s = 0;
    for (int r = rp; r < KK; r += 4)
        s += x[(size_t)(g * KK + r) * 512 + c0 + c];
    red[rp][c] = s;
    __syncthreads();
    if (rp == 0)
        pooled[g * 512 + c0 + c] = red[0][c] + red[1][c] + red[2][c] + red[3][c];
}

// ---------------- small FC + relu ----------------
__global__ void k_fc(const float* __restrict__ in, const float* __restrict__ W,
                     const float* __restrict__ bias, float* out, int fi, int fo) {
    __shared__ float row[512];
    int g = blockIdx.x, tid = threadIdx.x;
    for (int k = tid; k < fi; k += blockDim.x) row[k] = in[g * fi + k];
    __syncthreads();
    if (tid < fo) {
        float acc = bias[tid];
        for (int k = 0; k < fi; ++k) acc += row[k] * W[k * fo + tid];
        out[g * fo + tid] = acc > 0.0f ? acc : 0.0f;
    }
}

// ---------------- FC3 + log_softmax ----------------
__global__ void k_fc3(const float* __restrict__ in, const float* __restrict__ W,
                      const float* __restrict__ bias, float* out) {
    __shared__ float row[256];
    __shared__ float logits[100];
    __shared__ float red[128];
    int g = blockIdx.x, tid = threadIdx.x;  // 128 threads
    for (int k = tid; k < 256; k += 128) row[k] = in[g * 256 + k];
    __syncthreads();
    float v = -INFINITY;
    if (tid < 100) {
        float acc = bias[tid];
        for (int k = 0; k < 256; ++k) acc += row[k] * W[k * 100 + tid];
        logits[tid] = acc;
        v = acc;
    }
    red[tid] = v;
    __syncthreads();
    for (int s = 64; s > 0; s >>= 1) {
        if (tid < s) red[tid] = fmaxf(red[tid], red[tid + s]);
        __syncthreads();
    }
    float mx = red[0];
    __syncthreads();
    red[tid] = (tid < 100) ? expf(logits[tid] - mx) : 0.0f;
    __syncthreads();
    for (int s = 64; s > 0; s >>= 1) {
        if (tid < s) red[tid] += red[tid + s];
        __syncthreads();
    }
    float lse = logf(red[0]);
    if (tid < 100) out[g * 100 + tid] = logits[tid] - mx - lse;
}

// ---------------- launch ----------------
extern "C" void kernel_launch(void* const* d_in, const int* in_sizes, int n_in,
                              void* d_out, int out_size, void* d_ws, size_t ws_size,
                              hipStream_t stream) {
    const float* pos = (const float*)d_in[0];
    const int* ei = (const int*)d_in[1];
    const float* p = (const float*)d_in[3];
    const float *W[5], *bb[5], *gg[5], *be[5];
    for (int i = 0; i < 5; ++i) {
        W[i]  = (const float*)d_in[4 + 4 * i];
        bb[i] = (const float*)d_in[5 + 4 * i];
        gg[i] = (const float*)d_in[6 + 4 * i];
        be[i] = (const float*)d_in[7 + 4 * i];
    }
    const float* fw1 = (const float*)d_in[24]; const float* fb1 = (const float*)d_in[25];
    const float* fw2 = (const float*)d_in[26]; const float* fb2 = (const float*)d_in[27];
    const float* fw3 = (const float*)d_in[28]; const float* fb3 = (const float*)d_in[29];
    float* out = (float*)d_out;

    size_t off = 0;
    char* base = (char*)d_ws;
    auto alloc = [&](size_t bytes) { char* q = base + off; off += (bytes + 255) & ~(size_t)255; return q; };

    float* P0    = (float*)alloc((size_t)NN * 512 * 4);
    float* P1    = (float*)alloc((size_t)NN * 512 * 4);   // H scratch
    int*   remap = (int*)alloc((size_t)NTOT * 4);
    int*   deg   = (int*)alloc(NN * 4);
    int*   esrc  = (int*)alloc((size_t)NE * 4);
    int*   edst  = (int*)alloc((size_t)NE * 4);
    float* enorm = (float*)alloc((size_t)NE * 4);
    int*   cnt   = (int*)alloc(256);
    float* psum  = (float*)alloc((size_t)BN1_CHUNKS * 512 * 4);
    float* psq   = (float*)alloc((size_t)BN1_CHUNKS * 512 * 4);
    float* scale = (float*)alloc(512 * 4);
    float* shift = (float*)alloc(512 * 4);
    float* pooled= (float*)alloc(8 * 512 * 4);
    float* t1    = (float*)alloc(8 * 256 * 4);
    float* t2    = (float*)alloc(8 * 256 * 4);
    size_t need_P2 = off + (size_t)NN * 512 * 4;
    bool fused = (ws_size >= need_P2);
    float* P2 = fused ? (float*)alloc((size_t)NN * 512 * 4) : nullptr;

    k_init<<<NTOT / 256, 256, 0, stream>>>(remap, deg, cnt);
    k_topk2<<<BGR, 1024, 0, stream>>>(pos, p, remap, P0);
    k_edges<<<NE / 256, 256, 0, stream>>>(ei, remap, esrc, edst, deg, cnt);
    k_enorm<<<256, 256, 0, stream>>>(esrc, edst, deg, enorm, cnt);

    const int fins[5]  = {3, 64, 128, 128, 256};
    const int fouts[5] = {64, 128, 128, 256, 512};
    float* cur = P0;
    for (int l = 0; l < 5; ++l) {
        int fi = fins[l], fo = fouts[l];
        dim3 mg(NN / BM, fo / BNT);
        float* Y;
        if (fused) {
            Y = (cur == P0) ? P2 : P0;
            k_mm<<<mg, 256, 0, stream>>>(cur, W[l], deg, bb[l], P1, Y, fi, fo);
        } else {
            Y = cur;  // safe: selfbias runs after mm fully read cur
            k_mm<<<mg, 256, 0, stream>>>(cur, W[l], deg, bb[l], P1, nullptr, fi, fo);
            int tot = NN * fo;
            k_selfbias<<<(tot + 255) / 256, 256, 0, stream>>>(P1, deg, bb[l], Y, fo);
        }
        int logf_ = (fo == 64) ? 6 : (fo == 128) ? 7 : (fo == 256) ? 8 : 9;
        k_scatter<<<2048, 256, 0, stream>>>(P1, esrc, edst, enorm, Y, cnt, fo, logf_);
        k_bn1<<<BN1_CHUNKS, 256, 0, stream>>>(Y, psum, psq, fo);
        k_bn2<<<(fo + 255) / 256, 256, 0, stream>>>(psum, psq, gg[l], be[l], scale, shift, fo);
        k_bnapply<<<(NN * fo) / 1024, 256, 0, stream>>>(Y, scale, shift, fo);
        cur = Y;
    }

    k_pool<<<64, 256, 0, stream>>>(cur, pooled);
    k_fc<<<8, 256, 0, stream>>>(pooled, fw1, fb1, t1, 512, 256);
    k_fc<<<8, 256, 0, stream>>>(t1, fw2, fb2, t2, 256, 256);
    k_fc3<<<8, 128, 0, stream>>>(t2, fw3, fb3, out);
}